// Round 7
// baseline (18.502 us; speedup 1.0000x reference)
//
#include <hip/hip_runtime.h>
#include <hip/hip_bf16.h>

// Problem: B=64, Cin=64, Cout=128, H=W=64, K=3.
// ConvTranspose2d(stride=1,pad=0) -> spatial mean factorizes:
//   gap[b,o] = (1/4356) * sum_i Sx[b,i] * Sw[i,o] + bias[o]
//   out[b]   = 10 * logsumexp_o(gap[b,o])
// Two kernels; kernel boundary = free global barrier.
// PLAIN loads (no nontemporal): x (67 MB) becomes LLC-resident across
// graph replays (R5 evidence: FETCH_SIZE ~0 on some replays) -> stream
// from Infinity Cache, not HBM.

#define HW 4096          // 64*64 spatial elements per (b,i) row
#define CIN 64
#define COUT 128
#define BATCH 64
#define INV_AREA (1.0f / 4356.0f)   // 1/(66*66)

typedef float f4 __attribute__((ext_vector_type(4)));

// ---------------- Kernel 1: spatial sums of x + Sw side-duty -----------
// One block per (b*Cin + i) row of 4096 floats. 256 threads, 4x f4 each.
// Blocks 0..31 additionally compute 256 Sw entries each (8192 total).
__global__ __launch_bounds__(256) void spatial_sum_kernel(
    const float* __restrict__ x, const float* __restrict__ weight,
    float* __restrict__ sx, float* __restrict__ sws)
{
    const int row = blockIdx.x;                  // 0 .. 4095
    const int t = threadIdx.x;

    // Side duty: Sw[p], p = i*128+o. 32 blocks x 256 threads = 8192 entries.
    if (row < (CIN * COUT) / 256) {
        const int p = row * 256 + t;
        const float* wp = weight + (size_t)p * 9;
        float sw = 0.0f;
#pragma unroll
        for (int k = 0; k < 9; ++k) sw += wp[k];
        sws[p] = sw;                             // kernel boundary publishes
    }

    const f4* p4 = reinterpret_cast<const f4*>(x) + (size_t)row * (HW / 4);
    float s = 0.0f;
#pragma unroll
    for (int k = 0; k < 4; ++k) {
        f4 v = p4[t + k * 256];                  // plain load -> LLC-allocating
        s += (v.x + v.y) + (v.z + v.w);
    }
    // intra-wave (64-lane) butterfly reduce
#pragma unroll
    for (int off = 32; off > 0; off >>= 1)
        s += __shfl_xor(s, off, 64);

    __shared__ float wsum[4];
    const int wid  = t >> 6;
    const int lane = t & 63;
    if (lane == 0) wsum[wid] = s;
    __syncthreads();
    if (t == 0)
        sx[row] = (wsum[0] + wsum[1]) + (wsum[2] + wsum[3]);
}

// ---------------- Kernel 2: gap + logsumexp epilogue -------------------
// One block per batch b; 128 threads = one per output channel o.
__global__ __launch_bounds__(128) void gap_lse_kernel(
    const float* __restrict__ sx,      // (B, Cin)
    const float* __restrict__ sws,     // (Cin, Cout) pre-summed kernel taps
    const float* __restrict__ bias,    // (Cout)
    float* __restrict__ out)           // (B)
{
    const int b = blockIdx.x;
    const int o = threadIdx.x;         // 0 .. 127

    __shared__ float sxs[CIN];
    if (o < CIN) sxs[o] = sx[b * CIN + o];
    __syncthreads();

    // 64 independent coalesced L2-hit loads, fully unrolled.
    float acc = 0.0f;
#pragma unroll
    for (int i = 0; i < CIN; ++i)
        acc = fmaf(sxs[i], sws[i * COUT + o], acc);
    const float gap = fmaf(acc, INV_AREA, bias[o]);

    // logsumexp across 128 threads (2 waves)
    float m = gap;
#pragma unroll
    for (int off = 32; off > 0; off >>= 1)
        m = fmaxf(m, __shfl_xor(m, off, 64));

    __shared__ float wmax[2], wacc[2];
    const int wid = o >> 6;
    if ((o & 63) == 0) wmax[wid] = m;
    __syncthreads();
    const float M = fmaxf(wmax[0], wmax[1]);

    float e = __expf(gap - M);
#pragma unroll
    for (int off = 32; off > 0; off >>= 1)
        e += __shfl_xor(e, off, 64);
    if ((o & 63) == 0) wacc[wid] = e;
    __syncthreads();

    if (o == 0)
        out[b] = 10.0f * (logf(wacc[0] + wacc[1]) + M);
}

extern "C" void kernel_launch(void* const* d_in, const int* in_sizes, int n_in,
                              void* d_out, int out_size, void* d_ws, size_t ws_size,
                              hipStream_t stream) {
    const float* x      = (const float*)d_in[0];  // (64,64,64,64)
    const float* weight = (const float*)d_in[1];  // (64,128,3,3)
    const float* bias   = (const float*)d_in[2];  // (128,1,1)
    float* out = (float*)d_out;                   // 64 floats
    float* sx  = (float*)d_ws;                    // (64,64) scratch
    float* sws = (float*)d_ws + BATCH * CIN;      // (64,128) scratch

    spatial_sum_kernel<<<BATCH * CIN, 256, 0, stream>>>(x, weight, sx, sws);
    gap_lse_kernel<<<BATCH, 128, 0, stream>>>(sx, sws, bias, out);
}

// Round 8
// 16.161 us; speedup vs baseline: 1.1448x; 1.1448x over previous
//
#include <hip/hip_runtime.h>
#include <hip/hip_bf16.h>

// Problem: B=64, Cin=64, Cout=128, H=W=64, K=3.
// ConvTranspose2d(stride=1,pad=0) -> spatial mean factorizes:
//   gap[b,o] = (1/4356) * sum_i Sx[b,i] * Sw[i,o] + bias[o]
//   out[b]   = 10 * logsumexp_o(gap[b,o])
// Two kernels; kernel boundary = free global barrier.
// NT loads (R7 showed plain loads cost +2.5us). 2 rows/block to halve
// the per-block reduce-tail count vs R3.

#define HW 4096          // 64*64 spatial elements per (b,i) row
#define CIN 64
#define COUT 128
#define BATCH 64
#define INV_AREA (1.0f / 4356.0f)   // 1/(66*66)

typedef float f4 __attribute__((ext_vector_type(4)));
typedef float f2 __attribute__((ext_vector_type(2)));

// ---------------- Kernel 1: spatial sums of x + Sw side-duty -----------
// 2048 blocks x 256 threads; block handles rows 2*blk and 2*blk+1
// (8 NT f4 loads/thread, two accumulators, one shared reduce tail).
// Blocks 0..31 additionally compute 256 Sw entries each (8192 total).
__global__ __launch_bounds__(256) void spatial_sum_kernel(
    const float* __restrict__ x, const float* __restrict__ weight,
    float* __restrict__ sx, float* __restrict__ sws)
{
    const int blk = blockIdx.x;                  // 0 .. 2047
    const int t   = threadIdx.x;

    // Side duty: Sw[p], p = i*128+o. 32 blocks x 256 threads = 8192 entries.
    if (blk < (CIN * COUT) / 256) {
        const int p = blk * 256 + t;
        const float* wp = weight + (size_t)p * 9;
        float sw = 0.0f;
#pragma unroll
        for (int k = 0; k < 9; ++k) sw += wp[k];
        sws[p] = sw;                             // kernel boundary publishes
    }

    const int r0 = blk * 2;
    const f4* pA = reinterpret_cast<const f4*>(x) + (size_t)r0 * (HW / 4);
    const f4* pB = pA + (HW / 4);

    float sA = 0.0f, sB = 0.0f;
#pragma unroll
    for (int k = 0; k < 4; ++k) {
        f4 a = __builtin_nontemporal_load(&pA[t + k * 256]);
        f4 b = __builtin_nontemporal_load(&pB[t + k * 256]);
        sA += (a.x + a.y) + (a.z + a.w);
        sB += (b.x + b.y) + (b.z + b.w);
    }
#pragma unroll
    for (int off = 32; off > 0; off >>= 1) {
        sA += __shfl_xor(sA, off, 64);
        sB += __shfl_xor(sB, off, 64);
    }

    __shared__ float wsumA[4], wsumB[4];
    const int wid  = t >> 6;
    const int lane = t & 63;
    if (lane == 0) { wsumA[wid] = sA; wsumB[wid] = sB; }
    __syncthreads();
    if (t == 0) {
        f2 r;
        r.x = (wsumA[0] + wsumA[1]) + (wsumA[2] + wsumA[3]);
        r.y = (wsumB[0] + wsumB[1]) + (wsumB[2] + wsumB[3]);
        *reinterpret_cast<f2*>(&sx[r0]) = r;     // r0 even -> 8B aligned
    }
}

// ---------------- Kernel 2: gap + logsumexp epilogue -------------------
// One block per batch b; 128 threads = one per output channel o.
__global__ __launch_bounds__(128) void gap_lse_kernel(
    const float* __restrict__ sx,      // (B, Cin)
    const float* __restrict__ sws,     // (Cin, Cout) pre-summed kernel taps
    const float* __restrict__ bias,    // (Cout)
    float* __restrict__ out)           // (B)
{
    const int b = blockIdx.x;
    const int o = threadIdx.x;         // 0 .. 127

    __shared__ float sxs[CIN];
    if (o < CIN) sxs[o] = sx[b * CIN + o];
    __syncthreads();

    // 64 independent coalesced L2-hit loads, fully unrolled.
    float acc = 0.0f;
#pragma unroll
    for (int i = 0; i < CIN; ++i)
        acc = fmaf(sxs[i], sws[i * COUT + o], acc);
    const float gap = fmaf(acc, INV_AREA, bias[o]);

    // logsumexp across 128 threads (2 waves)
    float m = gap;
#pragma unroll
    for (int off = 32; off > 0; off >>= 1)
        m = fmaxf(m, __shfl_xor(m, off, 64));

    __shared__ float wmax[2], wacc[2];
    const int wid = o >> 6;
    if ((o & 63) == 0) wmax[wid] = m;
    __syncthreads();
    const float M = fmaxf(wmax[0], wmax[1]);

    float e = __expf(gap - M);
#pragma unroll
    for (int off = 32; off > 0; off >>= 1)
        e += __shfl_xor(e, off, 64);
    if ((o & 63) == 0) wacc[wid] = e;
    __syncthreads();

    if (o == 0)
        out[b] = 10.0f * (logf(wacc[0] + wacc[1]) + M);
}

extern "C" void kernel_launch(void* const* d_in, const int* in_sizes, int n_in,
                              void* d_out, int out_size, void* d_ws, size_t ws_size,
                              hipStream_t stream) {
    const float* x      = (const float*)d_in[0];  // (64,64,64,64)
    const float* weight = (const float*)d_in[1];  // (64,128,3,3)
    const float* bias   = (const float*)d_in[2];  // (128,1,1)
    float* out = (float*)d_out;                   // 64 floats
    float* sx  = (float*)d_ws;                    // (64,64) scratch
    float* sws = (float*)d_ws + BATCH * CIN;      // (64,128) scratch

    spatial_sum_kernel<<<(BATCH * CIN) / 2, 256, 0, stream>>>(x, weight, sx, sws);
    gap_lse_kernel<<<BATCH, 128, 0, stream>>>(sx, sws, bias, out);
}